// Round 5
// baseline (293.750 us; speedup 1.0000x reference)
//
#include <hip/hip_runtime.h>
#include <hip/hip_bf16.h>
#include <hip/hip_cooperative_groups.h>

namespace cg = cooperative_groups;

#define BDIM 8
#define LDIM 128
#define TDIM 64
#define NFEAT 1024
#define HNUM 16
#define DH 64

#define GM 4096  // rows of pooled = B*T*B
#define GN 1024
#define GK 1024

typedef __attribute__((ext_vector_type(8))) short short8;
typedef __attribute__((ext_vector_type(4))) float f32x4;

// round-to-nearest-even f32 -> bf16 bits
__device__ __forceinline__ unsigned short f2bf(float x) {
  union { float f; unsigned u; } v; v.f = x;
  unsigned r = v.u + 0x7fffu + ((v.u >> 16) & 1u);
  return (unsigned short)(r >> 16);
}

__device__ __forceinline__ void gload_lds16(const void* g, void* l) {
  __builtin_amdgcn_global_load_lds((const __attribute__((address_space(1))) void*)g,
                                   (__attribute__((address_space(3))) void*)l, 16, 0, 0);
}

// ---------------------------------------------------------------------------
// Kernel 1: mean (row bl) + weff (row f=bl).  1024 blocks x 256 -> 16 waves/CU
// (memory-bound phase needs high occupancy: R4 showed 4 waves/CU -> 16% BW).
// ---------------------------------------------------------------------------
__global__ __launch_bounds__(256) void mean_weff_kernel(
    const float* __restrict__ kv, const float* __restrict__ Wo,
    const float* __restrict__ Wv, const float* __restrict__ bv,
    const float* __restrict__ bo, float* __restrict__ km,
    unsigned short* __restrict__ Weff, float* __restrict__ beff) {
  __shared__ float worow[NFEAT];
  __shared__ float red[256];
  const int bl = blockIdx.x;
  const int tid = threadIdx.x;
  // ---- mean over t of kv[bl, t, :] ----
  {
    const float* src = kv + (size_t)bl * (TDIM * NFEAT) + tid * 4;
    float4 acc = make_float4(0.f, 0.f, 0.f, 0.f);
    for (int t0 = 0; t0 < TDIM; t0 += 8) {
      float4 v[8];
#pragma unroll
      for (int jj = 0; jj < 8; ++jj)
        v[jj] = *(const float4*)(src + (t0 + jj) * NFEAT);
#pragma unroll
      for (int jj = 0; jj < 8; ++jj) {
        acc.x += v[jj].x; acc.y += v[jj].y; acc.z += v[jj].z; acc.w += v[jj].w;
      }
    }
    const float s = 1.f / TDIM;
    const float4 o = make_float4(acc.x * s, acc.y * s, acc.z * s, acc.w * s);
    *(float4*)(km + (size_t)bl * NFEAT + tid * 4) = o;
  }
  // ---- weff row f = bl ----
  {
    const int f = bl;
    *(float4*)(worow + tid * 4) = *(const float4*)(Wo + (size_t)f * NFEAT + tid * 4);
    __syncthreads();
    const int g0 = tid * 4;
    const int hbase = (g0 >> 6) << 6;
    const int i0 = g0 & 63;
    float a0 = 0, a1 = 0, a2 = 0, a3 = 0;
#pragma unroll 4
    for (int d = 0; d < DH; ++d) {
      const float wod = worow[hbase + d];
      const float4 wv4 = *(const float4*)(Wv + d * DH + i0);
      a0 += wod * wv4.x; a1 += wod * wv4.y; a2 += wod * wv4.z; a3 += wod * wv4.w;
    }
    ushort4 pk;
    pk.x = f2bf(a0); pk.y = f2bf(a1); pk.z = f2bf(a2); pk.w = f2bf(a3);
    *(ushort4*)(Weff + (size_t)f * NFEAT + g0) = pk;
    red[tid] = worow[g0 + 0] * bv[i0 + 0] + worow[g0 + 1] * bv[i0 + 1] +
               worow[g0 + 2] * bv[i0 + 2] + worow[g0 + 3] * bv[i0 + 3];
    __syncthreads();
    for (int sft = 128; sft > 0; sft >>= 1) {
      if (tid < sft) red[tid] += red[tid + sft];
      __syncthreads();
    }
    if (tid == 0) beff[f] = bo[f] + red[0];
  }
}

// ---------------------------------------------------------------------------
// Phase: attn (R4-proven body; blocks 0..127 act, threads 0..127 act)
// ---------------------------------------------------------------------------
__device__ void attn_phase(char* smem_raw, int blk, int tid,
                           const float* __restrict__ q,
                           const float* __restrict__ km,
                           const float* __restrict__ Wq,
                           const float* __restrict__ bq,
                           const float* __restrict__ Wk,
                           float* __restrict__ attnW) {
  float* smf = (float*)smem_raw;
  float* qp_s = smf;          // 512
  float* qk_s = smf + 512;    // 512
  float* sw   = smf + 1024;   // 1024
  float* mred = smf + 2048;   // 8
  float* ired = smf + 2056;   // 8
  const int b1 = blk >> 4;
  const int h  = blk & 15;
  const bool act = (blk < 128) && (tid < 128);
  if (act) {
    const int e0 = tid * 4;
    const int b2 = e0 >> 6;
    const int d0 = e0 & 63;
    float a0 = bq[d0], a1 = bq[d0 + 1], a2 = bq[d0 + 2], a3 = bq[d0 + 3];
    const float* qrow = q + b2 * NFEAT + h * DH;
#pragma unroll 4
    for (int i = 0; i < DH; ++i) {
      const float qv = qrow[i];
      a0 += qv * Wq[(d0 + 0) * DH + i];
      a1 += qv * Wq[(d0 + 1) * DH + i];
      a2 += qv * Wq[(d0 + 2) * DH + i];
      a3 += qv * Wq[(d0 + 3) * DH + i];
    }
    qp_s[e0 + 0] = a0; qp_s[e0 + 1] = a1; qp_s[e0 + 2] = a2; qp_s[e0 + 3] = a3;
  }
  __syncthreads();
  if (act) {
    const int e0 = tid * 4;
    const int b2 = e0 >> 6;
    const int i0 = e0 & 63;
    float a0 = 0, a1 = 0, a2 = 0, a3 = 0;
#pragma unroll 4
    for (int d = 0; d < DH; ++d) {
      const float qpv = qp_s[b2 * DH + d];
      const float4 wk4 = *(const float4*)(Wk + d * DH + i0);
      a0 += qpv * wk4.x; a1 += qpv * wk4.y; a2 += qpv * wk4.z; a3 += qpv * wk4.w;
    }
    qk_s[e0 + 0] = a0; qk_s[e0 + 1] = a1; qk_s[e0 + 2] = a2; qk_s[e0 + 3] = a3;
  }
  __syncthreads();
  if (act) {
    const float* kmrow = km + (size_t)(b1 * LDIM + tid) * NFEAT + h * DH;
    float s[8] = {0, 0, 0, 0, 0, 0, 0, 0};
#pragma unroll
    for (int i4 = 0; i4 < DH / 4; ++i4) {
      const float4 kmv = *(const float4*)(kmrow + i4 * 4);
#pragma unroll
      for (int b2 = 0; b2 < 8; ++b2) {
        const float4 qk4 = *(const float4*)(qk_s + b2 * DH + i4 * 4);
        s[b2] += kmv.x * qk4.x + kmv.y * qk4.y + kmv.z * qk4.z + kmv.w * qk4.w;
      }
    }
#pragma unroll
    for (int b2 = 0; b2 < 8; ++b2) sw[b2 * LDIM + tid] = s[b2] * 0.125f;
  }
  __syncthreads();
  if (act && tid < 8) {
    const int b2 = tid;
    float m = -1e30f;
    for (int j = 0; j < LDIM; ++j) m = fmaxf(m, sw[b2 * LDIM + j]);
    float ssum = 0.f;
    for (int j = 0; j < LDIM; ++j) ssum += expf(sw[b2 * LDIM + j] - m);
    mred[b2] = m;
    ired[b2] = 1.f / ssum;
  }
  __syncthreads();
  if (act) {
    float* abase = attnW + ((size_t)(b1 * HNUM + h) * BDIM) * LDIM + tid;
#pragma unroll
    for (int b2 = 0; b2 < 8; ++b2)
      abase[b2 * LDIM] = expf(sw[b2 * LDIM + tid] - mred[b2]) * ired[b2];
  }
}

// ---------------------------------------------------------------------------
// Phase: pool.  One (b1,t) slice per block, 256 threads (full NFEAT).
// attn tile in LDS as [b2][h][l ^ xr], xr=(h&3)<<3: float4 transpose-writes
// contiguous (conflict-free) and 4 h-group broadcast reads hit 4 distinct
// banks (conflict-free).  Exactly 64 KB.
// ---------------------------------------------------------------------------
__device__ void pool_phase(char* smem_raw, int blk, int tid,
                           const float* __restrict__ kv,
                           const float* __restrict__ attnW,
                           unsigned short* __restrict__ pooled) {
  float* alds = (float*)smem_raw;  // 16384 floats
  const int b1 = blk & 7;          // consecutive blocks spread across XCDs share b1 per XCD
  const int t  = blk >> 3;
#pragma unroll
  for (int j = 0; j < 16; ++j) {
    const int fl = j * 256 + tid;  // f4-index over [h][b2][l4]
    const int l4 = fl & 31;
    const int b2 = (fl >> 5) & 7;
    const int h  = fl >> 8;
    const float4 a4 = *(const float4*)(attnW +
        ((size_t)(b1 * HNUM + h) * BDIM + b2) * LDIM + l4 * 4);
    *(float4*)(alds + (b2 * 16 + h) * 128 + ((l4 * 4) ^ ((h & 3) << 3))) = a4;
  }
  __syncthreads();
  const int f0 = tid * 4;
  const int h  = tid >> 4;
  const int xr = (h & 3) << 3;
  const float* kvb = kv + ((size_t)(b1 * LDIM) * TDIM + t) * NFEAT + f0;
  float4 acc[8];
#pragma unroll
  for (int b2 = 0; b2 < 8; ++b2) acc[b2] = make_float4(0.f, 0.f, 0.f, 0.f);
  for (int l0 = 0; l0 < LDIM; l0 += 8) {
    float4 v[8];
#pragma unroll
    for (int jj = 0; jj < 8; ++jj)
      v[jj] = *(const float4*)(kvb + (size_t)(l0 + jj) * (TDIM * NFEAT));
#pragma unroll
    for (int jj = 0; jj < 8; ++jj) {
      const int lx = (l0 + jj) ^ xr;
#pragma unroll
      for (int b2 = 0; b2 < 8; ++b2) {
        const float w = alds[(b2 * 16 + h) * 128 + lx];
        acc[b2].x += w * v[jj].x; acc[b2].y += w * v[jj].y;
        acc[b2].z += w * v[jj].z; acc[b2].w += w * v[jj].w;
      }
    }
  }
  unsigned short* obase = pooled + ((size_t)(b1 * TDIM + t) * BDIM) * NFEAT + f0;
#pragma unroll
  for (int b2 = 0; b2 < 8; ++b2) {
    ushort4 pk;
    pk.x = f2bf(acc[b2].x); pk.y = f2bf(acc[b2].y);
    pk.z = f2bf(acc[b2].z); pk.w = f2bf(acc[b2].w);
    *(ushort4*)(obase + b2 * NFEAT) = pk;
  }
}

// ---------------------------------------------------------------------------
// Phase: bf16 MFMA gemm, one 128x64 tile per block (R3-proven body).
// ---------------------------------------------------------------------------
__device__ void gemm_phase(char* smem_raw, int blk, int tid,
                           const unsigned short* __restrict__ A,
                           const unsigned short* __restrict__ W,
                           const float* __restrict__ beff,
                           float* __restrict__ out) {
  unsigned short* As = (unsigned short*)smem_raw;            // 2 x 4096 elems
  unsigned short* Bs = (unsigned short*)(smem_raw + 16384);  // 2 x 2048 elems
  const int w = tid >> 6, l = tid & 63;
  const int wr = w >> 1, wc = w & 1;
  const int mBase = (blk >> 4) * 128;
  const int nBase = (blk & 15) * 64;
  int arow[2], acol[2];
#pragma unroll
  for (int j = 0; j < 2; ++j) {
    const int cid = j * 256 + tid;
    const int r = cid >> 2, c = cid & 3;
    arow[j] = r;
    acol[j] = (c ^ ((r >> 1) & 3)) * 8;
  }
  const int brow = tid >> 2;
  const int bcol = ((tid & 3) ^ ((brow >> 1) & 3)) * 8;
  const int rl = l & 15, ks = l >> 4;
  const int fsel = (ks ^ ((rl >> 1) & 3)) * 16;

  f32x4 acc[4][2] = {};
#pragma unroll
  for (int j = 0; j < 2; ++j)
    gload_lds16(A + (size_t)(mBase + arow[j]) * GK + acol[j],
                (char*)As + (j * 256 + tid) * 16);
  gload_lds16(W + (size_t)(nBase + brow) * GK + bcol, (char*)Bs + tid * 16);
  __syncthreads();
  int cur = 0;
  for (int t = 0; t < GK / 32; ++t) {
    if (t + 1 < GK / 32) {
      const int k0 = (t + 1) * 32;
#pragma unroll
      for (int j = 0; j < 2; ++j)
        gload_lds16(A + (size_t)(mBase + arow[j]) * GK + k0 + acol[j],
                    (char*)(As + (cur ^ 1) * 4096) + (j * 256 + tid) * 16);
      gload_lds16(W + (size_t)(nBase + brow) * GK + k0 + bcol,
                  (char*)(Bs + (cur ^ 1) * 2048) + tid * 16);
    }
    short8 a[4], b[2];
#pragma unroll
    for (int m = 0; m < 4; ++m)
      a[m] = *(const short8*)((const char*)(As + cur * 4096) +
                              (wr * 64 + m * 16 + rl) * 64 + fsel);
#pragma unroll
    for (int n = 0; n < 2; ++n)
      b[n] = *(const short8*)((const char*)(Bs + cur * 2048) +
                              (wc * 32 + n * 16 + rl) * 64 + fsel);
#pragma unroll
    for (int m = 0; m < 4; ++m)
#pragma unroll
      for (int n = 0; n < 2; ++n)
        acc[m][n] = __builtin_amdgcn_mfma_f32_16x16x32_bf16(a[m], b[n], acc[m][n], 0, 0, 0);
    __syncthreads();
    cur ^= 1;
  }
#pragma unroll
  for (int n = 0; n < 2; ++n) {
    const int col = nBase + wc * 32 + n * 16 + rl;
    const float bvv = beff[col];
#pragma unroll
    for (int m = 0; m < 4; ++m) {
      const int row0 = mBase + wr * 64 + m * 16 + ks * 4;
#pragma unroll
      for (int j2 = 0; j2 < 4; ++j2)
        out[(size_t)(row0 + j2) * GN + col] = acc[m][n][j2] + bvv;
    }
  }
}

// ---------------------------------------------------------------------------
// Cooperative kernel: attn -> pool -> gemm.  512 blocks x 256 = 2 blocks/CU
// (8 waves/CU for the memory-bound pool; gemm gets cross-block overlap).
// ---------------------------------------------------------------------------
__global__ __launch_bounds__(256, 2) void fused3_kernel(
    const float* __restrict__ q, const float* __restrict__ kv,
    const float* __restrict__ Wq, const float* __restrict__ bq,
    const float* __restrict__ Wk, const float* __restrict__ km,
    float* __restrict__ attnW, const unsigned short* __restrict__ Weff,
    const float* __restrict__ beff, unsigned short* __restrict__ pooled,
    float* __restrict__ out) {
  __shared__ char smem[65536];
  cg::grid_group grid = cg::this_grid();
  attn_phase(smem, blockIdx.x, threadIdx.x, q, km, Wq, bq, Wk, attnW);
  grid.sync();
  pool_phase(smem, blockIdx.x, threadIdx.x, kv, attnW, pooled);
  grid.sync();
  gemm_phase(smem, blockIdx.x, threadIdx.x, pooled, Weff, beff, out);
}

// ---- fallback standalone kernels (if cooperative launch is refused) --------
__global__ __launch_bounds__(256) void attn_sep(
    const float* __restrict__ q, const float* __restrict__ km,
    const float* __restrict__ Wq, const float* __restrict__ bq,
    const float* __restrict__ Wk, float* __restrict__ attnW) {
  __shared__ char smem[16384];
  attn_phase(smem, blockIdx.x, threadIdx.x, q, km, Wq, bq, Wk, attnW);
}
__global__ __launch_bounds__(256) void pool_sep(
    const float* __restrict__ kv, const float* __restrict__ attnW,
    unsigned short* __restrict__ pooled) {
  __shared__ char smem[65536];
  pool_phase(smem, blockIdx.x, threadIdx.x, kv, attnW, pooled);
}
__global__ __launch_bounds__(256) void gemm_sep(
    const unsigned short* __restrict__ A, const unsigned short* __restrict__ W,
    const float* __restrict__ beff, float* __restrict__ out) {
  __shared__ char smem[24576];
  gemm_phase(smem, blockIdx.x, threadIdx.x, A, W, beff, out);
}

extern "C" void kernel_launch(void* const* d_in, const int* in_sizes, int n_in,
                              void* d_out, int out_size, void* d_ws, size_t ws_size,
                              hipStream_t stream) {
  const float* q  = (const float*)d_in[0];
  const float* kv = (const float*)d_in[1];
  const float* Wq = (const float*)d_in[2];
  const float* bq = (const float*)d_in[3];
  const float* Wk = (const float*)d_in[4];
  // d_in[5] = bk: dropped (constant shift per softmax row -> no effect)
  const float* Wv = (const float*)d_in[6];
  const float* bv = (const float*)d_in[7];
  const float* Wo = (const float*)d_in[8];
  const float* bo = (const float*)d_in[9];
  float* out = (float*)d_out;

  char* ws = (char*)d_ws;
  float*          km     = (float*)ws;                                // 4 MB
  float*          attnW  = (float*)(ws + (4u << 20));                 // 512 KB
  float*          beff   = (float*)(ws + (4u << 20) + (512u << 10));  // 4 KB
  unsigned short* Weff   = (unsigned short*)(ws + (4u << 20) + (516u << 10));               // 2 MB
  unsigned short* pooled = (unsigned short*)(ws + (4u << 20) + (516u << 10) + (2u << 20));  // 8 MB

  mean_weff_kernel<<<BDIM * LDIM, 256, 0, stream>>>(kv, Wo, Wv, bv, bo, km, Weff, beff);

  void* args[] = {(void*)&q,    (void*)&kv,   (void*)&Wq,     (void*)&bq,
                  (void*)&Wk,   (void*)&km,   (void*)&attnW,  (void*)&Weff,
                  (void*)&beff, (void*)&pooled, (void*)&out};
  hipError_t e = hipLaunchCooperativeKernel((void*)fused3_kernel, dim3(512),
                                            dim3(256), args, 0, stream);
  if (e != hipSuccess) {
    attn_sep<<<128, 256, 0, stream>>>(q, km, Wq, bq, Wk, attnW);
    pool_sep<<<512, 256, 0, stream>>>(kv, attnW, pooled);
    gemm_sep<<<512, 256, 0, stream>>>(pooled, Weff, beff, out);
  }
}

// Round 6
// 137.061 us; speedup vs baseline: 2.1432x; 2.1432x over previous
//
#include <hip/hip_runtime.h>
#include <hip/hip_bf16.h>

#define BDIM 8
#define LDIM 128
#define TDIM 64
#define NFEAT 1024
#define HNUM 16
#define DH 64

#define GM 4096  // rows of pooled = B*T*B
#define GN 1024
#define GK 1024

typedef __attribute__((ext_vector_type(8))) short short8;
typedef __attribute__((ext_vector_type(4))) float f32x4;

// round-to-nearest-even f32 -> bf16 bits
__device__ __forceinline__ unsigned short f2bf(float x) {
  union { float f; unsigned u; } v; v.f = x;
  unsigned r = v.u + 0x7fffu + ((v.u >> 16) & 1u);
  return (unsigned short)(r >> 16);
}

__device__ __forceinline__ void gload_lds16(const void* g, void* l) {
  __builtin_amdgcn_global_load_lds((const __attribute__((address_space(1))) void*)g,
                                   (__attribute__((address_space(3))) void*)l, 16, 0, 0);
}

// ---------------------------------------------------------------------------
// Kernel 1: mean (row bl) + weff (row f=bl).  1024 blocks x 256 = 16 waves/CU.
// (R5-validated body: weff rides free behind mean's HBM stream.)
// ---------------------------------------------------------------------------
__global__ __launch_bounds__(256) void mean_weff_kernel(
    const float* __restrict__ kv, const float* __restrict__ Wo,
    const float* __restrict__ Wv, const float* __restrict__ bv,
    const float* __restrict__ bo, float* __restrict__ km,
    unsigned short* __restrict__ Weff, float* __restrict__ beff) {
  __shared__ float worow[NFEAT];
  __shared__ float red[256];
  const int bl = blockIdx.x;
  const int tid = threadIdx.x;
  // ---- mean over t of kv[bl, t, :] ----
  {
    const float* src = kv + (size_t)bl * (TDIM * NFEAT) + tid * 4;
    float4 acc = make_float4(0.f, 0.f, 0.f, 0.f);
    for (int t0 = 0; t0 < TDIM; t0 += 8) {
      float4 v[8];
#pragma unroll
      for (int jj = 0; jj < 8; ++jj)
        v[jj] = *(const float4*)(src + (t0 + jj) * NFEAT);
#pragma unroll
      for (int jj = 0; jj < 8; ++jj) {
        acc.x += v[jj].x; acc.y += v[jj].y; acc.z += v[jj].z; acc.w += v[jj].w;
      }
    }
    const float s = 1.f / TDIM;
    const float4 o = make_float4(acc.x * s, acc.y * s, acc.z * s, acc.w * s);
    *(float4*)(km + (size_t)bl * NFEAT + tid * 4) = o;
  }
  // ---- weff row f = bl ----
  {
    const int f = bl;
    *(float4*)(worow + tid * 4) = *(const float4*)(Wo + (size_t)f * NFEAT + tid * 4);
    __syncthreads();
    const int g0 = tid * 4;
    const int hbase = (g0 >> 6) << 6;
    const int i0 = g0 & 63;
    float a0 = 0, a1 = 0, a2 = 0, a3 = 0;
#pragma unroll 4
    for (int d = 0; d < DH; ++d) {
      const float wod = worow[hbase + d];
      const float4 wv4 = *(const float4*)(Wv + d * DH + i0);
      a0 += wod * wv4.x; a1 += wod * wv4.y; a2 += wod * wv4.z; a3 += wod * wv4.w;
    }
    ushort4 pk;
    pk.x = f2bf(a0); pk.y = f2bf(a1); pk.z = f2bf(a2); pk.w = f2bf(a3);
    *(ushort4*)(Weff + (size_t)f * NFEAT + g0) = pk;
    red[tid] = worow[g0 + 0] * bv[i0 + 0] + worow[g0 + 1] * bv[i0 + 1] +
               worow[g0 + 2] * bv[i0 + 2] + worow[g0 + 3] * bv[i0 + 3];
    __syncthreads();
    for (int sft = 128; sft > 0; sft >>= 1) {
      if (tid < sft) red[tid] += red[tid + sft];
      __syncthreads();
    }
    if (tid == 0) beff[f] = bo[f] + red[0];
  }
}

// ---------------------------------------------------------------------------
// Kernel 2: fused q-proj, k-proj (folded), QK^T, softmax -> attn[b1,h,b2,l]
// One block per (b1,h), 128 threads. Softmax reduction now wave-parallel:
// group g=tid>>4 owns row b2=g (16 lanes, 8 strided elems each + shfl_xor).
// ---------------------------------------------------------------------------
__global__ __launch_bounds__(128) void attn_kernel(const float* __restrict__ q,
                                                   const float* __restrict__ km,
                                                   const float* __restrict__ Wq,
                                                   const float* __restrict__ bq,
                                                   const float* __restrict__ Wk,
                                                   float* __restrict__ attn) {
  __shared__ float qp_s[BDIM * DH];
  __shared__ float qk_s[BDIM * DH];
  __shared__ float sw[BDIM * LDIM];
  __shared__ float mred[BDIM], ired[BDIM];
  const int b1 = blockIdx.x;
  const int h  = blockIdx.y;
  const int tid = threadIdx.x;

  {
    const int e0 = tid * 4;
    const int b2 = e0 >> 6;
    const int d0 = e0 & 63;
    float a0 = bq[d0], a1 = bq[d0 + 1], a2 = bq[d0 + 2], a3 = bq[d0 + 3];
    const float* qrow = q + b2 * NFEAT + h * DH;
#pragma unroll 4
    for (int i = 0; i < DH; ++i) {
      const float qv = qrow[i];
      a0 += qv * Wq[(d0 + 0) * DH + i];
      a1 += qv * Wq[(d0 + 1) * DH + i];
      a2 += qv * Wq[(d0 + 2) * DH + i];
      a3 += qv * Wq[(d0 + 3) * DH + i];
    }
    qp_s[e0 + 0] = a0; qp_s[e0 + 1] = a1; qp_s[e0 + 2] = a2; qp_s[e0 + 3] = a3;
  }
  __syncthreads();
  {
    const int e0 = tid * 4;
    const int b2 = e0 >> 6;
    const int i0 = e0 & 63;
    float a0 = 0, a1 = 0, a2 = 0, a3 = 0;
#pragma unroll 4
    for (int d = 0; d < DH; ++d) {
      const float qpv = qp_s[b2 * DH + d];
      const float4 wk4 = *(const float4*)(Wk + d * DH + i0);
      a0 += qpv * wk4.x; a1 += qpv * wk4.y; a2 += qpv * wk4.z; a3 += qpv * wk4.w;
    }
    qk_s[e0 + 0] = a0; qk_s[e0 + 1] = a1; qk_s[e0 + 2] = a2; qk_s[e0 + 3] = a3;
  }
  __syncthreads();
  {
    const float* kmrow = km + (size_t)(b1 * LDIM + tid) * NFEAT + h * DH;
    float s[8] = {0, 0, 0, 0, 0, 0, 0, 0};
#pragma unroll
    for (int i4 = 0; i4 < DH / 4; ++i4) {
      const float4 kmv = *(const float4*)(kmrow + i4 * 4);
#pragma unroll
      for (int b2 = 0; b2 < 8; ++b2) {
        const float4 qk4 = *(const float4*)(qk_s + b2 * DH + i4 * 4);
        s[b2] += kmv.x * qk4.x + kmv.y * qk4.y + kmv.z * qk4.z + kmv.w * qk4.w;
      }
    }
#pragma unroll
    for (int b2 = 0; b2 < 8; ++b2) sw[b2 * LDIM + tid] = s[b2] * 0.125f;
  }
  __syncthreads();
  // wave-parallel softmax reduction (replaces 8-lane serial 128-iter chains)
  {
    const int g = tid >> 4;   // b2 row owned by this 16-lane group
    const int r = tid & 15;
    float m = -1e30f;
#pragma unroll
    for (int k = 0; k < 8; ++k) m = fmaxf(m, sw[g * LDIM + r + k * 16]);
#pragma unroll
    for (int s = 1; s < 16; s <<= 1) m = fmaxf(m, __shfl_xor(m, s, 64));
    float ssum = 0.f;
#pragma unroll
    for (int k = 0; k < 8; ++k) ssum += expf(sw[g * LDIM + r + k * 16] - m);
#pragma unroll
    for (int s = 1; s < 16; s <<= 1) ssum += __shfl_xor(ssum, s, 64);
    if (r == 0) { mred[g] = m; ired[g] = 1.f / ssum; }
  }
  __syncthreads();
  {
    float* abase = attn + ((size_t)(b1 * HNUM + h) * BDIM) * LDIM + tid;
#pragma unroll
    for (int b2 = 0; b2 < 8; ++b2)
      abase[b2 * LDIM] = expf(sw[b2 * LDIM + tid] - mred[b2]) * ired[b2];
  }
}

// ---------------------------------------------------------------------------
// Kernel 3: pool (R3-proven body, verbatim).
// pooled[b1][t][b2][f] = sum_l attn[b1, f/64, b2, l] * kv[b1,l,t,f]
// ---------------------------------------------------------------------------
#define HSTRIDE 1032
__global__ __launch_bounds__(64) void pool_kernel(const float* __restrict__ kv,
                                                  const float* __restrict__ attn,
                                                  unsigned short* __restrict__ pooled) {
  __shared__ float wlds[4 * HSTRIDE];
  const int b1 = blockIdx.x;
  const int t = blockIdx.y;
  const int ftile = blockIdx.z;
  const int tid = threadIdx.x;
  {
#pragma unroll
    for (int hg = 0; hg < 4; ++hg) {
      const float* src = attn + ((size_t)(b1 * HNUM + ftile * 4 + hg)) * (BDIM * LDIM);
#pragma unroll
      for (int j = 0; j < 4; ++j) {
        const int idx = (j * 64 + tid) * 4;
        *(float4*)(wlds + hg * HSTRIDE + idx) = *(const float4*)(src + idx);
      }
    }
  }
  __syncthreads();
  const int f = ftile * 256 + tid * 4;
  const int hh = tid >> 4;
  const float* kvbase = kv + ((size_t)b1 * LDIM) * (TDIM * NFEAT) + t * NFEAT + f;
  float4 acc[8];
#pragma unroll
  for (int b2 = 0; b2 < 8; ++b2) acc[b2] = make_float4(0.f, 0.f, 0.f, 0.f);
  const float* wbase = wlds + hh * HSTRIDE;
  for (int l0 = 0; l0 < LDIM; l0 += 8) {
    float4 v[8];
#pragma unroll
    for (int j = 0; j < 8; ++j)
      v[j] = *(const float4*)(kvbase + (size_t)(l0 + j) * (TDIM * NFEAT));
#pragma unroll
    for (int j = 0; j < 8; ++j) {
#pragma unroll
      for (int b2 = 0; b2 < 8; ++b2) {
        const float w = wbase[b2 * LDIM + l0 + j];
        acc[b2].x += w * v[j].x; acc[b2].y += w * v[j].y;
        acc[b2].z += w * v[j].z; acc[b2].w += w * v[j].w;
      }
    }
  }
  unsigned short* obase = pooled + ((size_t)(b1 * TDIM + t) * BDIM) * NFEAT + f;
#pragma unroll
  for (int b2 = 0; b2 < 8; ++b2) {
    ushort4 pk;
    pk.x = f2bf(acc[b2].x); pk.y = f2bf(acc[b2].y);
    pk.z = f2bf(acc[b2].z); pk.w = f2bf(acc[b2].w);
    *(ushort4*)(obase + b2 * NFEAT) = pk;
  }
}

// ---------------------------------------------------------------------------
// Kernel 4: bf16 MFMA GEMM (R3-proven body, verbatim).
// 128x64 tile, BK=32, LDS double-buffer, both-sides XOR swizzle.
// ---------------------------------------------------------------------------
__global__ __launch_bounds__(256) void mfma_gemm(const unsigned short* __restrict__ A,
                                                 const unsigned short* __restrict__ W,
                                                 const float* __restrict__ beff,
                                                 float* __restrict__ out) {
  __shared__ unsigned short As[2][128 * 32];
  __shared__ unsigned short Bs[2][64 * 32];
  const int tid = threadIdx.x;
  const int w = tid >> 6, l = tid & 63;
  const int mBase = blockIdx.y * 128, nBase = blockIdx.x * 64;
  const int wr = w >> 1, wc = w & 1;

  int arow[2], acol[2];
#pragma unroll
  for (int j = 0; j < 2; ++j) {
    const int cid = j * 256 + tid;
    const int r = cid >> 2, c = cid & 3;
    arow[j] = r;
    acol[j] = (c ^ ((r >> 1) & 3)) * 8;
  }
  const int brow = tid >> 2;
  const int bcol = ((tid & 3) ^ ((brow >> 1) & 3)) * 8;

  const int rl = l & 15, ks = l >> 4;
  const int fsel = (ks ^ ((rl >> 1) & 3)) * 16;

  f32x4 acc[4][2] = {};

#pragma unroll
  for (int j = 0; j < 2; ++j)
    gload_lds16(A + (size_t)(mBase + arow[j]) * GK + acol[j],
                (char*)As[0] + (j * 256 + tid) * 16);
  gload_lds16(W + (size_t)(nBase + brow) * GK + bcol, (char*)Bs[0] + tid * 16);
  __syncthreads();

  int cur = 0;
  for (int t = 0; t < GK / 32; ++t) {
    if (t + 1 < GK / 32) {
      const int k0 = (t + 1) * 32;
#pragma unroll
      for (int j = 0; j < 2; ++j)
        gload_lds16(A + (size_t)(mBase + arow[j]) * GK + k0 + acol[j],
                    (char*)As[cur ^ 1] + (j * 256 + tid) * 16);
      gload_lds16(W + (size_t)(nBase + brow) * GK + k0 + bcol,
                  (char*)Bs[cur ^ 1] + tid * 16);
    }
    short8 a[4], b[2];
#pragma unroll
    for (int m = 0; m < 4; ++m)
      a[m] = *(const short8*)((const char*)As[cur] + (wr * 64 + m * 16 + rl) * 64 + fsel);
#pragma unroll
    for (int n = 0; n < 2; ++n)
      b[n] = *(const short8*)((const char*)Bs[cur] + (wc * 32 + n * 16 + rl) * 64 + fsel);
#pragma unroll
    for (int m = 0; m < 4; ++m)
#pragma unroll
      for (int n = 0; n < 2; ++n)
        acc[m][n] = __builtin_amdgcn_mfma_f32_16x16x32_bf16(a[m], b[n], acc[m][n], 0, 0, 0);
    __syncthreads();
    cur ^= 1;
  }

#pragma unroll
  for (int n = 0; n < 2; ++n) {
    const int col = nBase + wc * 32 + n * 16 + rl;
    const float bv = beff[col];
#pragma unroll
    for (int m = 0; m < 4; ++m) {
      const int row0 = mBase + wr * 64 + m * 16 + ks * 4;
#pragma unroll
      for (int j2 = 0; j2 < 4; ++j2)
        out[(size_t)(row0 + j2) * GN + col] = acc[m][n][j2] + bv;
    }
  }
}

extern "C" void kernel_launch(void* const* d_in, const int* in_sizes, int n_in,
                              void* d_out, int out_size, void* d_ws, size_t ws_size,
                              hipStream_t stream) {
  const float* q  = (const float*)d_in[0];
  const float* kv = (const float*)d_in[1];
  const float* Wq = (const float*)d_in[2];
  const float* bq = (const float*)d_in[3];
  const float* Wk = (const float*)d_in[4];
  // d_in[5] = bk: dropped (constant shift per softmax row -> no effect)
  const float* Wv = (const float*)d_in[6];
  const float* bv = (const float*)d_in[7];
  const float* Wo = (const float*)d_in[8];
  const float* bo = (const float*)d_in[9];
  float* out = (float*)d_out;

  char* ws = (char*)d_ws;
  float*          km     = (float*)ws;                                // 4 MB
  float*          attnW  = (float*)(ws + (4u << 20));                 // 512 KB
  float*          beff   = (float*)(ws + (4u << 20) + (512u << 10));  // 4 KB
  unsigned short* Weff   = (unsigned short*)(ws + (4u << 20) + (516u << 10));               // 2 MB
  unsigned short* pooled = (unsigned short*)(ws + (4u << 20) + (516u << 10) + (2u << 20));  // 8 MB

  mean_weff_kernel<<<BDIM * LDIM, 256, 0, stream>>>(kv, Wo, Wv, bv, bo, km, Weff, beff);
  attn_kernel<<<dim3(BDIM, HNUM), 128, 0, stream>>>(q, km, Wq, bq, Wk, attnW);
  pool_kernel<<<dim3(BDIM, TDIM, 4), 64, 0, stream>>>(kv, attnW, pooled);
  mfma_gemm<<<dim3(GN / 64, GM / 128), 256, 0, stream>>>(pooled, Weff, beff, out);
}